// Round 1
// baseline (517.558 us; speedup 1.0000x reference)
//
#include <hip/hip_runtime.h>
#include <hip/hip_fp16.h>

#define IN_DIM 256
#define HID_DIM 128
#define OUT_DIM 64

typedef short s8v __attribute__((ext_vector_type(8)));
typedef float f32x4 __attribute__((ext_vector_type(4)));

// ---------------- bf16 split helpers ----------------

__device__ __forceinline__ unsigned short bf16_rne(float f) {
    unsigned int u = __float_as_uint(f);
    u += 0x7FFFu + ((u >> 16) & 1u);
    return (unsigned short)(u >> 16);
}
__device__ __forceinline__ float bfbits_to_f(unsigned short h) {
    return __uint_as_float(((unsigned int)h) << 16);
}
__device__ __forceinline__ void cvt_split4(float4 f, uint2& hv, uint2& lv) {
    unsigned short h0 = bf16_rne(f.x), h1 = bf16_rne(f.y);
    unsigned short h2 = bf16_rne(f.z), h3 = bf16_rne(f.w);
    unsigned short l0 = bf16_rne(f.x - bfbits_to_f(h0));
    unsigned short l1 = bf16_rne(f.y - bfbits_to_f(h1));
    unsigned short l2 = bf16_rne(f.z - bfbits_to_f(h2));
    unsigned short l3 = bf16_rne(f.w - bfbits_to_f(h3));
    hv.x = (unsigned int)h0 | ((unsigned int)h1 << 16);
    hv.y = (unsigned int)h2 | ((unsigned int)h3 << 16);
    lv.x = (unsigned int)l0 | ((unsigned int)l1 << 16);
    lv.y = (unsigned int)l2 | ((unsigned int)l3 << 16);
}

// 8 consecutive floats -> hi/lo bf16 fragments (s8v = 8 shorts = one MFMA operand)
__device__ __forceinline__ void cvt_split8(float4 f0, float4 f1, s8v& hi, s8v& lo) {
    uint2 h0, l0, h1, l1;
    cvt_split4(f0, h0, l0);
    cvt_split4(f1, h1, l1);
    uint4 h = make_uint4(h0.x, h0.y, h1.x, h1.y);
    uint4 l = make_uint4(l0.x, l0.y, l1.x, l1.y);
    hi = *(s8v*)&h;
    lo = *(s8v*)&l;
}

__global__ __launch_bounds__(256) void wsplit_kernel(const float* __restrict__ W,
        unsigned short* __restrict__ wth, unsigned short* __restrict__ wtl,
        int K, int NCOL) {
    int idx = blockIdx.x * 256 + threadIdx.x;
    if (idx < K * NCOL) {
        int k = idx / NCOL, nn = idx % NCOL;
        float f = W[idx];
        unsigned short h = bf16_rne(f);
        unsigned short l = bf16_rne(f - bfbits_to_f(h));
        wth[nn * K + k] = h;
        wtl[nn * K + k] = l;
    }
}

// ---------------- preprocessing ----------------
// packed[i]: bits [63:40] = edge count, bits [39:0] = fixed-point (2^-24) sum of w.

#define FPSCALE 16777216.0f
#define FPMASK  ((1ULL << 40) - 1)

__global__ __launch_bounds__(256) void init_kernel(unsigned long long* packed, int n) {
    int i = blockIdx.x * 256 + threadIdx.x;
    if (i < n) packed[i] = (1ULL << 24);      // deg = 1.0 (self-loop), cnt = 0
}

// One u64 atomic per edge; the RETURN VALUE's cnt field is this edge's
// arrival index at its destination -> deterministic CSC slot later (no 2nd atomic).
__global__ __launch_bounds__(256) void deg_cnt_kernel(const int* __restrict__ col,
        const float* __restrict__ w, unsigned long long* packed,
        int* __restrict__ arr, int e) {
    int i = blockIdx.x * 256 + threadIdx.x;
    if (i < e) {
        unsigned long long v = (1ULL << 40) |
            (unsigned long long)(w[i] * FPSCALE + 0.5f);
        unsigned long long old = atomicAdd(&packed[col[i]], v);
        arr[i] = (int)(old >> 40);
    }
}

__global__ __launch_bounds__(256) void dinv_kernel(const unsigned long long* __restrict__ packed,
        float* __restrict__ dinv, int* __restrict__ cnt, int n) {
    int i = blockIdx.x * 256 + threadIdx.x;
    if (i < n) {
        unsigned long long p = packed[i];
        float d = (float)(p & FPMASK) * (1.0f / FPSCALE);
        dinv[i] = d > 0.0f ? rsqrtf(d) : 0.0f;
        cnt[i] = (int)(p >> 40);
    }
}

// ---- hierarchical exclusive scan ----

__global__ __launch_bounds__(256) void scan1_kernel(const int* __restrict__ cnt,
        int* __restrict__ bsum, int n) {
    int t = threadIdx.x;
    int base = blockIdx.x * 1024 + t * 4;
    int s = 0;
    if (base + 3 < n) {
        int4 v = *(const int4*)(cnt + base);
        s = v.x + v.y + v.z + v.w;
    } else {
        for (int i = 0; i < 4; i++) if (base + i < n) s += cnt[base + i];
    }
    __shared__ int sm[256];
    sm[t] = s;
    __syncthreads();
    for (int d = 1; d < 256; d <<= 1) {
        int v = (t >= d) ? sm[t - d] : 0;
        __syncthreads();
        sm[t] += v;
        __syncthreads();
    }
    if (t == 255) bsum[blockIdx.x] = sm[255];
}

__global__ __launch_bounds__(1024) void scan2_kernel(int* bsum, int* total_out, int nb) {
    __shared__ int sm[1024];
    int t = threadIdx.x;
    int v = (t < nb) ? bsum[t] : 0;
    sm[t] = v;
    __syncthreads();
    for (int d = 1; d < 1024; d <<= 1) {
        int u = (t >= d) ? sm[t - d] : 0;
        __syncthreads();
        sm[t] += u;
        __syncthreads();
    }
    int ex = (t == 0) ? 0 : sm[t - 1];
    if (t < nb) bsum[t] = ex;
    if (t == nb - 1) *total_out = sm[t];
}

__global__ __launch_bounds__(256) void scan3_kernel(const int* __restrict__ cnt,
        const int* __restrict__ bsum, int* __restrict__ offsets, int n) {
    int t = threadIdx.x;
    int base = blockIdx.x * 1024 + t * 4;
    int a[4] = {0, 0, 0, 0};
    if (base + 3 < n) {
        int4 v = *(const int4*)(cnt + base);
        a[0] = v.x; a[1] = v.y; a[2] = v.z; a[3] = v.w;
    } else {
        for (int i = 0; i < 4; i++) if (base + i < n) a[i] = cnt[base + i];
    }
    int s = a[0] + a[1] + a[2] + a[3];
    __shared__ int sm[256];
    sm[t] = s;
    __syncthreads();
    for (int d = 1; d < 256; d <<= 1) {
        int u = (t >= d) ? sm[t - d] : 0;
        __syncthreads();
        sm[t] += u;
        __syncthreads();
    }
    int pre = bsum[blockIdx.x] + ((t == 0) ? 0 : sm[t - 1]);
    int o0 = pre, o1 = o0 + a[0], o2 = o1 + a[1], o3 = o2 + a[2];
    if (base + 3 < n) {
        *(int4*)(offsets + base) = make_int4(o0, o1, o2, o3);
    } else {
        int o[4] = {o0, o1, o2, o3};
        for (int i = 0; i < 4; i++) if (base + i < n) offsets[base + i] = o[i];
    }
}

// CSC entry: int2{ src_row, float_bits(w) } — dinv folded elsewhere.
// No atomic: slot = offsets[col] + arrival index from deg_cnt.

__global__ __launch_bounds__(256) void fill_csc_kernel(const int* __restrict__ row,
        const int* __restrict__ col, const float* __restrict__ w,
        const int* __restrict__ offsets, const int* __restrict__ arr,
        int2* __restrict__ csc, int e) {
    int i = blockIdx.x * 256 + threadIdx.x;
    if (i < e) {
        int c = col[i];
        int p = offsets[c] + arr[i];
        csc[p] = make_int2(row[i], __float_as_int(w[i]));
    }
}

// ---------------- MFMA split-bf16 GEMM (fp16 output, row-scaled by dinv) ------
// LDS-free / barrier-free: each lane's MFMA A-fragment is 8 CONTIGUOUS floats of
// one x row (row = wave*32 + r16 (+16 for mi=1), k = kc*32 + quad*8), so it is
// loaded directly global->reg (each x element read exactly once chip-wide) and
// split-converted in-register. B fragments are 16B contiguous in the
// pre-transposed weight (tiny, L1/L2-resident, shared by all waves).
// No LDS => no barriers, no bank conflicts; one-chunk A register prefetch
// lets HBM latency hide under the MFMA of the previous chunk.

template<int K, int NCOL>
__global__ __launch_bounds__(256) void gemm_mfma_kernel(
        const float* __restrict__ x, const unsigned short* __restrict__ wth,
        const unsigned short* __restrict__ wtl, const float* __restrict__ dinv,
        __half* __restrict__ out, int n) {
    constexpr int NT = NCOL / 16;
    constexpr int NCH = K / 32;

    int t = threadIdx.x;
    int wave = t >> 6, lane = t & 63, quad = lane >> 4, r16 = lane & 15;
    long rowBase = (long)blockIdx.x * 128;

    f32x4 acc[2][NT];
#pragma unroll
    for (int mi = 0; mi < 2; mi++)
#pragma unroll
        for (int nt = 0; nt < NT; nt++) acc[mi][nt] = (f32x4)0.0f;

    long r0 = rowBase + wave * 32 + r16;       if (r0 > n - 1) r0 = n - 1;
    long r1 = rowBase + wave * 32 + 16 + r16;  if (r1 > n - 1) r1 = n - 1;
    const float* pa0 = x + r0 * K + quad * 8;
    const float* pa1 = x + r1 * K + quad * 8;
    const unsigned short* pbh = wth + (long)r16 * K + quad * 8;
    const unsigned short* pbl = wtl + (long)r16 * K + quad * 8;

    // prefetch chunk 0
    float4 a0 = *(const float4*)(pa0);
    float4 a1 = *(const float4*)(pa0 + 4);
    float4 a2 = *(const float4*)(pa1);
    float4 a3 = *(const float4*)(pa1 + 4);

    for (int kc = 0; kc < NCH; kc++) {
        s8v ah0, al0, ah1, al1;
        cvt_split8(a0, a1, ah0, al0);
        cvt_split8(a2, a3, ah1, al1);
        if (kc + 1 < NCH) {          // register prefetch of next chunk's A
            const float* q0 = pa0 + (kc + 1) * 32;
            const float* q1 = pa1 + (kc + 1) * 32;
            a0 = *(const float4*)(q0);
            a1 = *(const float4*)(q0 + 4);
            a2 = *(const float4*)(q1);
            a3 = *(const float4*)(q1 + 4);
        }
        const unsigned short* bkh = pbh + kc * 32;
        const unsigned short* bkl = pbl + kc * 32;
#pragma unroll
        for (int nt = 0; nt < NT; nt++) {
            s8v bh = *(const s8v*)(bkh + nt * 16 * K);
            s8v bl = *(const s8v*)(bkl + nt * 16 * K);
            acc[0][nt] = __builtin_amdgcn_mfma_f32_16x16x32_bf16(ah0, bh, acc[0][nt], 0, 0, 0);
            acc[0][nt] = __builtin_amdgcn_mfma_f32_16x16x32_bf16(al0, bh, acc[0][nt], 0, 0, 0);
            acc[0][nt] = __builtin_amdgcn_mfma_f32_16x16x32_bf16(ah0, bl, acc[0][nt], 0, 0, 0);
            acc[1][nt] = __builtin_amdgcn_mfma_f32_16x16x32_bf16(ah1, bh, acc[1][nt], 0, 0, 0);
            acc[1][nt] = __builtin_amdgcn_mfma_f32_16x16x32_bf16(al1, bh, acc[1][nt], 0, 0, 0);
            acc[1][nt] = __builtin_amdgcn_mfma_f32_16x16x32_bf16(ah1, bl, acc[1][nt], 0, 0, 0);
        }
    }
#pragma unroll
    for (int mi = 0; mi < 2; mi++) {
        long gr0 = rowBase + wave * 32 + mi * 16 + quad * 4;
#pragma unroll
        for (int nt = 0; nt < NT; nt++) {
            f32x4 d = acc[mi][nt];
#pragma unroll
            for (int i = 0; i < 4; i++) {
                long gr = gr0 + i;
                if (gr < n) out[gr * NCOL + nt * 16 + r16] =
                    __float2half(d[i] * dinv[gr]);
            }
        }
    }
}

// ---------------- fp16 gather accumulate helpers ----------------

__device__ __forceinline__ void acc8(float* a, uint4 raw, float w) {
    __half2* hp = (__half2*)&raw;
    float2 f0 = __half22float2(hp[0]);
    float2 f1 = __half22float2(hp[1]);
    float2 f2 = __half22float2(hp[2]);
    float2 f3 = __half22float2(hp[3]);
    a[0] += w * f0.x; a[1] += w * f0.y; a[2] += w * f1.x; a[3] += w * f1.y;
    a[4] += w * f2.x; a[5] += w * f2.y; a[6] += w * f3.x; a[7] += w * f3.y;
}

__device__ __forceinline__ void acc4h(float* a, uint2 raw, float w) {
    __half2* hp = (__half2*)&raw;
    float2 f0 = __half22float2(hp[0]);
    float2 f1 = __half22float2(hp[1]);
    a[0] += w * f0.x; a[1] += w * f0.y; a[2] += w * f1.x; a[3] += w * f1.y;
}

// ---------------- aggregation layer 1 (D=128 fp16 in, fp32 out, +bias, relu) ----
// h' rows are pre-scaled by dinv[src]; edge weight is raw w; final scale dinv[node].

__global__ __launch_bounds__(256) void agg1_kernel(const __half* __restrict__ h,
        const float* __restrict__ dinv, const int* __restrict__ offsets,
        const int2* __restrict__ csc, const float* __restrict__ b,
        float* __restrict__ out, int n) {
    int t = threadIdx.x;
    int lane = t & 63;
    int strm = lane >> 4;            // 0..3
    int li = lane & 15;              // half8 index in row (16*8 = 128 dims)
    int node = blockIdx.x * 4 + (t >> 6);
    if (node >= n) return;

    float a0[8] = {0,0,0,0,0,0,0,0};
    float a1[8] = {0,0,0,0,0,0,0,0};
    int s = offsets[node], e = offsets[node + 1];

    if (strm == 0) {                 // self-loop: weight 1 * h'[node]
        uint4 raw = ((const uint4*)(h + (long)node * HID_DIM))[li];
        acc8(a0, raw, 1.0f);
    }

    int p = s + strm;
    for (; p + 4 < e; p += 8) {
        int2 e0 = csc[p], e1 = csc[p + 4];
        uint4 r0 = ((const uint4*)(h + (long)e0.x * HID_DIM))[li];
        uint4 r1 = ((const uint4*)(h + (long)e1.x * HID_DIM))[li];
        acc8(a0, r0, __int_as_float(e0.y));
        acc8(a1, r1, __int_as_float(e1.y));
    }
    if (p < e) {
        int2 e0 = csc[p];
        uint4 r0 = ((const uint4*)(h + (long)e0.x * HID_DIM))[li];
        acc8(a0, r0, __int_as_float(e0.y));
    }
#pragma unroll
    for (int j = 0; j < 8; j++) a0[j] += a1[j];
#pragma unroll
    for (int j = 0; j < 8; j++) a0[j] += __shfl_down(a0[j], 32);
#pragma unroll
    for (int j = 0; j < 8; j++) a0[j] += __shfl_down(a0[j], 16);
    if (strm == 0) {
        float di = dinv[node];
        float4 bv0 = ((const float4*)b)[li * 2];
        float4 bv1 = ((const float4*)b)[li * 2 + 1];
        float4 o0 = make_float4(fmaxf(di * a0[0] + bv0.x, 0.f), fmaxf(di * a0[1] + bv0.y, 0.f),
                                fmaxf(di * a0[2] + bv0.z, 0.f), fmaxf(di * a0[3] + bv0.w, 0.f));
        float4 o1 = make_float4(fmaxf(di * a0[4] + bv1.x, 0.f), fmaxf(di * a0[5] + bv1.y, 0.f),
                                fmaxf(di * a0[6] + bv1.z, 0.f), fmaxf(di * a0[7] + bv1.w, 0.f));
        float4* dst = (float4*)(out + (long)node * HID_DIM);
        dst[li * 2] = o0;
        dst[li * 2 + 1] = o1;
    }
}

// ---------------- aggregation layer 2 (D=64 fp16 in, fp32 out, +bias) ----------

__global__ __launch_bounds__(256) void agg2_kernel(const __half* __restrict__ h,
        const float* __restrict__ dinv, const int* __restrict__ offsets,
        const int2* __restrict__ csc, const float* __restrict__ b,
        float* __restrict__ out, int n) {
    int t = threadIdx.x;
    int lane = t & 63;
    int strm = lane >> 4;            // 0..3
    int li = lane & 15;              // half4 index in row (16*4 = 64 dims)
    int node = blockIdx.x * 4 + (t >> 6);
    if (node >= n) return;

    float a0[4] = {0,0,0,0};
    float a1[4] = {0,0,0,0};
    int s = offsets[node], e = offsets[node + 1];

    if (strm == 0) {
        uint2 raw = ((const uint2*)(h + (long)node * OUT_DIM))[li];
        acc4h(a0, raw, 1.0f);
    }

    int p = s + strm;
    for (; p + 4 < e; p += 8) {
        int2 e0 = csc[p], e1 = csc[p + 4];
        uint2 r0 = ((const uint2*)(h + (long)e0.x * OUT_DIM))[li];
        uint2 r1 = ((const uint2*)(h + (long)e1.x * OUT_DIM))[li];
        acc4h(a0, r0, __int_as_float(e0.y));
        acc4h(a1, r1, __int_as_float(e1.y));
    }
    if (p < e) {
        int2 e0 = csc[p];
        uint2 r0 = ((const uint2*)(h + (long)e0.x * OUT_DIM))[li];
        acc4h(a0, r0, __int_as_float(e0.y));
    }
#pragma unroll
    for (int j = 0; j < 4; j++) a0[j] += a1[j];
#pragma unroll
    for (int j = 0; j < 4; j++) a0[j] += __shfl_down(a0[j], 32);
#pragma unroll
    for (int j = 0; j < 4; j++) a0[j] += __shfl_down(a0[j], 16);
    if (strm == 0) {
        float di = dinv[node];
        float4 bv = ((const float4*)b)[li];
        ((float4*)(out + (long)node * OUT_DIM))[li] =
            make_float4(di * a0[0] + bv.x, di * a0[1] + bv.y,
                        di * a0[2] + bv.z, di * a0[3] + bv.w);
    }
}

// ---------------- launch ----------------

extern "C" void kernel_launch(void* const* d_in, const int* in_sizes, int n_in,
                              void* d_out, int out_size, void* d_ws, size_t ws_size,
                              hipStream_t stream) {
    const float* x  = (const float*)d_in[0];
    const int*   ei = (const int*)d_in[1];
    const float* w  = (const float*)d_in[2];
    const float* W1 = (const float*)d_in[3];
    const float* b1 = (const float*)d_in[4];
    const float* W2 = (const float*)d_in[5];
    const float* b2 = (const float*)d_in[6];
    float* out = (float*)d_out;

    int N = in_sizes[0] / IN_DIM;       // 100000
    int E = in_sizes[2];                // 1600000
    const int* row = ei;
    const int* col = ei + E;

    char* base = (char*)d_ws;
    size_t off = 0;
    auto alloc = [&](size_t bytes) -> void* {
        void* p = base + off;
        off += (bytes + 255) & ~(size_t)255;
        return p;
    };
    unsigned long long* packed = (unsigned long long*)alloc((size_t)N * 8);
    float* dinv     = (float*)alloc((size_t)N * 4);
    int*   cnt      = (int*)  alloc((size_t)N * 4);
    int*   offsets  = (int*)  alloc((size_t)(N + 1) * 4);
    int*   arr      = (int*)  alloc((size_t)E * 4);
    int*   bsum     = (int*)  alloc((size_t)1024 * 4);
    int2*  csc      = (int2*) alloc((size_t)E * 8);
    __half* h       = (__half*)alloc((size_t)N * HID_DIM * 2);  // fp16; reused for h2
    float* hagg     = (float*)alloc((size_t)N * HID_DIM * 4);
    unsigned short* wt1h = (unsigned short*)alloc((size_t)IN_DIM * HID_DIM * 2);
    unsigned short* wt1l = (unsigned short*)alloc((size_t)IN_DIM * HID_DIM * 2);
    unsigned short* wt2h = (unsigned short*)alloc((size_t)HID_DIM * OUT_DIM * 2);
    unsigned short* wt2l = (unsigned short*)alloc((size_t)HID_DIM * OUT_DIM * 2);

    int gN = (N + 255) / 256;
    int gE = (E + 255) / 256;
    int gGemm = (N + 127) / 128;
    int gAgg = (N + 3) / 4;
    int nbScan = (N + 1023) / 1024;

    wsplit_kernel<<<(IN_DIM * HID_DIM + 255) / 256, 256, 0, stream>>>(
        W1, wt1h, wt1l, IN_DIM, HID_DIM);
    wsplit_kernel<<<(HID_DIM * OUT_DIM + 255) / 256, 256, 0, stream>>>(
        W2, wt2h, wt2l, HID_DIM, OUT_DIM);
    init_kernel<<<gN, 256, 0, stream>>>(packed, N);
    deg_cnt_kernel<<<gE, 256, 0, stream>>>(col, w, packed, arr, E);
    dinv_kernel<<<gN, 256, 0, stream>>>(packed, dinv, cnt, N);
    scan1_kernel<<<nbScan, 256, 0, stream>>>(cnt, bsum, N);
    scan2_kernel<<<1, 1024, 0, stream>>>(bsum, offsets + N, nbScan);
    scan3_kernel<<<nbScan, 256, 0, stream>>>(cnt, bsum, offsets, N);
    fill_csc_kernel<<<gE, 256, 0, stream>>>(row, col, w, offsets, arr, csc, E);
    gemm_mfma_kernel<IN_DIM, HID_DIM><<<gGemm, 256, 0, stream>>>(x, wt1h, wt1l, dinv, h, N);
    agg1_kernel<<<gAgg, 256, 0, stream>>>(h, dinv, offsets, csc, b1, hagg, N);
    gemm_mfma_kernel<HID_DIM, OUT_DIM><<<gGemm, 256, 0, stream>>>(hagg, wt2h, wt2l, dinv, h, N);
    agg2_kernel<<<gAgg, 256, 0, stream>>>(h, dinv, offsets, csc, b2, out, N);
}

// Round 2
// 480.816 us; speedup vs baseline: 1.0764x; 1.0764x over previous
//
#include <hip/hip_runtime.h>
#include <hip/hip_fp16.h>

#define IN_DIM 256
#define HID_DIM 128
#define OUT_DIM 64

typedef short s8v __attribute__((ext_vector_type(8)));
typedef float f32x4 __attribute__((ext_vector_type(4)));

// ---------------- bf16 split helpers ----------------

__device__ __forceinline__ unsigned short bf16_rne(float f) {
    unsigned int u = __float_as_uint(f);
    u += 0x7FFFu + ((u >> 16) & 1u);
    return (unsigned short)(u >> 16);
}
__device__ __forceinline__ float bfbits_to_f(unsigned short h) {
    return __uint_as_float(((unsigned int)h) << 16);
}
__device__ __forceinline__ void cvt_split4(float4 f, uint2& hv, uint2& lv) {
    unsigned short h0 = bf16_rne(f.x), h1 = bf16_rne(f.y);
    unsigned short h2 = bf16_rne(f.z), h3 = bf16_rne(f.w);
    unsigned short l0 = bf16_rne(f.x - bfbits_to_f(h0));
    unsigned short l1 = bf16_rne(f.y - bfbits_to_f(h1));
    unsigned short l2 = bf16_rne(f.z - bfbits_to_f(h2));
    unsigned short l3 = bf16_rne(f.w - bfbits_to_f(h3));
    hv.x = (unsigned int)h0 | ((unsigned int)h1 << 16);
    hv.y = (unsigned int)h2 | ((unsigned int)h3 << 16);
    lv.x = (unsigned int)l0 | ((unsigned int)l1 << 16);
    lv.y = (unsigned int)l2 | ((unsigned int)l3 << 16);
}

// 8 consecutive floats -> hi/lo bf16 fragments (s8v = 8 shorts = one MFMA operand)
__device__ __forceinline__ void cvt_split8(float4 f0, float4 f1, s8v& hi, s8v& lo) {
    uint2 h0, l0, h1, l1;
    cvt_split4(f0, h0, l0);
    cvt_split4(f1, h1, l1);
    uint4 h = make_uint4(h0.x, h0.y, h1.x, h1.y);
    uint4 l = make_uint4(l0.x, l0.y, l1.x, l1.y);
    hi = *(s8v*)&h;
    lo = *(s8v*)&l;
}

__global__ __launch_bounds__(256) void wsplit_kernel(const float* __restrict__ W,
        unsigned short* __restrict__ wth, unsigned short* __restrict__ wtl,
        int K, int NCOL) {
    int idx = blockIdx.x * 256 + threadIdx.x;
    if (idx < K * NCOL) {
        int k = idx / NCOL, nn = idx % NCOL;
        float f = W[idx];
        unsigned short h = bf16_rne(f);
        unsigned short l = bf16_rne(f - bfbits_to_f(h));
        wth[nn * K + k] = h;
        wtl[nn * K + k] = l;
    }
}

// ---------------- preprocessing ----------------
// packed[i]: bits [63:40] = edge count, bits [39:0] = fixed-point (2^-24) sum of w.

#define FPSCALE 16777216.0f
#define FPMASK  ((1ULL << 40) - 1)

__global__ __launch_bounds__(256) void init_kernel(unsigned long long* packed, int n) {
    int i = blockIdx.x * 256 + threadIdx.x;
    if (i < n) packed[i] = (1ULL << 24);      // deg = 1.0 (self-loop), cnt = 0
}

// One u64 atomic per edge; the RETURN VALUE's cnt field is this edge's
// arrival index at its destination -> deterministic CSC slot later (no 2nd atomic).
__global__ __launch_bounds__(256) void deg_cnt_kernel(const int* __restrict__ col,
        const float* __restrict__ w, unsigned long long* packed,
        int* __restrict__ arr, int e) {
    int i = blockIdx.x * 256 + threadIdx.x;
    if (i < e) {
        unsigned long long v = (1ULL << 40) |
            (unsigned long long)(w[i] * FPSCALE + 0.5f);
        unsigned long long old = atomicAdd(&packed[col[i]], v);
        arr[i] = (int)(old >> 40);
    }
}

__global__ __launch_bounds__(256) void dinv_kernel(const unsigned long long* __restrict__ packed,
        float* __restrict__ dinv, int* __restrict__ cnt, int n) {
    int i = blockIdx.x * 256 + threadIdx.x;
    if (i < n) {
        unsigned long long p = packed[i];
        float d = (float)(p & FPMASK) * (1.0f / FPSCALE);
        dinv[i] = d > 0.0f ? rsqrtf(d) : 0.0f;
        cnt[i] = (int)(p >> 40);
    }
}

// ---- hierarchical exclusive scan ----

__global__ __launch_bounds__(256) void scan1_kernel(const int* __restrict__ cnt,
        int* __restrict__ bsum, int n) {
    int t = threadIdx.x;
    int base = blockIdx.x * 1024 + t * 4;
    int s = 0;
    if (base + 3 < n) {
        int4 v = *(const int4*)(cnt + base);
        s = v.x + v.y + v.z + v.w;
    } else {
        for (int i = 0; i < 4; i++) if (base + i < n) s += cnt[base + i];
    }
    __shared__ int sm[256];
    sm[t] = s;
    __syncthreads();
    for (int d = 1; d < 256; d <<= 1) {
        int v = (t >= d) ? sm[t - d] : 0;
        __syncthreads();
        sm[t] += v;
        __syncthreads();
    }
    if (t == 255) bsum[blockIdx.x] = sm[255];
}

__global__ __launch_bounds__(1024) void scan2_kernel(int* bsum, int* total_out, int nb) {
    __shared__ int sm[1024];
    int t = threadIdx.x;
    int v = (t < nb) ? bsum[t] : 0;
    sm[t] = v;
    __syncthreads();
    for (int d = 1; d < 1024; d <<= 1) {
        int u = (t >= d) ? sm[t - d] : 0;
        __syncthreads();
        sm[t] += u;
        __syncthreads();
    }
    int ex = (t == 0) ? 0 : sm[t - 1];
    if (t < nb) bsum[t] = ex;
    if (t == nb - 1) *total_out = sm[t];
}

__global__ __launch_bounds__(256) void scan3_kernel(const int* __restrict__ cnt,
        const int* __restrict__ bsum, int* __restrict__ offsets, int n) {
    int t = threadIdx.x;
    int base = blockIdx.x * 1024 + t * 4;
    int a[4] = {0, 0, 0, 0};
    if (base + 3 < n) {
        int4 v = *(const int4*)(cnt + base);
        a[0] = v.x; a[1] = v.y; a[2] = v.z; a[3] = v.w;
    } else {
        for (int i = 0; i < 4; i++) if (base + i < n) a[i] = cnt[base + i];
    }
    int s = a[0] + a[1] + a[2] + a[3];
    __shared__ int sm[256];
    sm[t] = s;
    __syncthreads();
    for (int d = 1; d < 256; d <<= 1) {
        int u = (t >= d) ? sm[t - d] : 0;
        __syncthreads();
        sm[t] += u;
        __syncthreads();
    }
    int pre = bsum[blockIdx.x] + ((t == 0) ? 0 : sm[t - 1]);
    int o0 = pre, o1 = o0 + a[0], o2 = o1 + a[1], o3 = o2 + a[2];
    if (base + 3 < n) {
        *(int4*)(offsets + base) = make_int4(o0, o1, o2, o3);
    } else {
        int o[4] = {o0, o1, o2, o3};
        for (int i = 0; i < 4; i++) if (base + i < n) offsets[base + i] = o[i];
    }
}

// CSC entry: int2{ src_row, float_bits(w) } — dinv folded elsewhere.
// No atomic: slot = offsets[col] + arrival index from deg_cnt.

__global__ __launch_bounds__(256) void fill_csc_kernel(const int* __restrict__ row,
        const int* __restrict__ col, const float* __restrict__ w,
        const int* __restrict__ offsets, const int* __restrict__ arr,
        int2* __restrict__ csc, int e) {
    int i = blockIdx.x * 256 + threadIdx.x;
    if (i < e) {
        int c = col[i];
        int p = offsets[c] + arr[i];
        csc[p] = make_int2(row[i], __float_as_int(w[i]));
    }
}

// ---------------- MFMA split-bf16 GEMM (fp16 output, row-scaled by dinv) ------
// Hybrid staging (post-mortem of r0/r1):
//  * A (the streamed 100K x K matrix): direct global->reg, one-chunk register
//    prefetch, split-converted in-register. No LDS for A (each element feeds
//    exactly one lane: zero cross-lane reuse; LDS round-trip was 2 barriers +
//    4-way write conflicts in the 80us version).
//  * B (tiny weight matrix): staged per-K-chunk into LDS via global_load_lds
//    (linear lane*16B dest -> conflict-free; no VGPR round-trip), double
//    buffered, ONE barrier per chunk. ds_read_b128 B-fragments get
//    compiler-pipelined lgkmcnt — this removes the serialized per-nt
//    L2-latency chain that made the LDS-free version (r1, 107us) slow: at
//    88 VGPRs the compiler couldn't hoist 16 global B loads per chunk.

template<int K, int NCOL>
__global__ __launch_bounds__(256) void gemm_mfma_kernel(
        const float* __restrict__ x, const unsigned short* __restrict__ wth,
        const unsigned short* __restrict__ wtl, const float* __restrict__ dinv,
        __half* __restrict__ out, int n) {
    constexpr int NT = NCOL / 16;
    constexpr int NCH = K / 32;
    constexpr int SEG_PER_WAVE = NT / 4;   // 16-row segments each wave stages

    // B chunk: [buf][col][32 k-shorts]; rows are 64B -> even bank spread for
    // both the lane*16 linear write and the (row, quad*8) read.
    __shared__ unsigned short sBh[2][NCOL][32];
    __shared__ unsigned short sBl[2][NCOL][32];

    int t = threadIdx.x;
    int wave = t >> 6, lane = t & 63, quad = lane >> 4, r16 = lane & 15;
    long rowBase = (long)blockIdx.x * 128;

    f32x4 acc[2][NT];
#pragma unroll
    for (int mi = 0; mi < 2; mi++)
#pragma unroll
        for (int nt = 0; nt < NT; nt++) acc[mi][nt] = (f32x4)0.0f;

    long r0 = rowBase + wave * 32 + r16;       if (r0 > n - 1) r0 = n - 1;
    long r1 = rowBase + wave * 32 + 16 + r16;  if (r1 > n - 1) r1 = n - 1;
    const float* pa0 = x + r0 * K + quad * 8;
    const float* pa1 = x + r1 * K + quad * 8;

    int l4 = lane >> 2;            // 0..15 : row within 16-row segment
    int c8 = (lane & 3) * 8;       // 0,8,16,24 : short offset within 32-short chunk

    // stage B chunk kc into buffer buf: each wave issues 2*SEG_PER_WAVE
    // global_load_lds (wave-uniform LDS base, per-lane global source).
    auto stage = [&](int buf, int kc) {
#pragma unroll
        for (int j = 0; j < SEG_PER_WAVE; j++) {
            int s = wave + 4 * j;                 // 16-row segment id
            int r = s * 16 + l4;                  // B row (= output col)
            const unsigned short* gh = wth + (long)r * K + kc * 32 + c8;
            const unsigned short* gl = wtl + (long)r * K + kc * 32 + c8;
            __builtin_amdgcn_global_load_lds(
                (const __attribute__((address_space(1))) unsigned int*)gh,
                (__attribute__((address_space(3))) unsigned int*)&sBh[buf][s * 16][0],
                16, 0, 0);
            __builtin_amdgcn_global_load_lds(
                (const __attribute__((address_space(1))) unsigned int*)gl,
                (__attribute__((address_space(3))) unsigned int*)&sBl[buf][s * 16][0],
                16, 0, 0);
        }
    };

    // prologue: stage chunk 0, prefetch A chunk 0
    stage(0, 0);
    float4 a0 = *(const float4*)(pa0);
    float4 a1 = *(const float4*)(pa0 + 4);
    float4 a2 = *(const float4*)(pa1);
    float4 a3 = *(const float4*)(pa1 + 4);
    __syncthreads();

    for (int kc = 0; kc < NCH; kc++) {
        int buf = kc & 1;
        if (kc + 1 < NCH) stage(buf ^ 1, kc + 1);   // B prefetch in flight over MFMA

        s8v ah0, al0, ah1, al1;
        cvt_split8(a0, a1, ah0, al0);
        cvt_split8(a2, a3, ah1, al1);
        if (kc + 1 < NCH) {                          // A register prefetch
            const float* q0 = pa0 + (kc + 1) * 32;
            const float* q1 = pa1 + (kc + 1) * 32;
            a0 = *(const float4*)(q0);
            a1 = *(const float4*)(q0 + 4);
            a2 = *(const float4*)(q1);
            a3 = *(const float4*)(q1 + 4);
        }
#pragma unroll
        for (int nt = 0; nt < NT; nt++) {
            s8v bh = *(const s8v*)&sBh[buf][nt * 16 + r16][quad * 8];
            s8v bl = *(const s8v*)&sBl[buf][nt * 16 + r16][quad * 8];
            acc[0][nt] = __builtin_amdgcn_mfma_f32_16x16x32_bf16(ah0, bh, acc[0][nt], 0, 0, 0);
            acc[0][nt] = __builtin_amdgcn_mfma_f32_16x16x32_bf16(al0, bh, acc[0][nt], 0, 0, 0);
            acc[0][nt] = __builtin_amdgcn_mfma_f32_16x16x32_bf16(ah0, bl, acc[0][nt], 0, 0, 0);
            acc[1][nt] = __builtin_amdgcn_mfma_f32_16x16x32_bf16(ah1, bh, acc[1][nt], 0, 0, 0);
            acc[1][nt] = __builtin_amdgcn_mfma_f32_16x16x32_bf16(al1, bh, acc[1][nt], 0, 0, 0);
            acc[1][nt] = __builtin_amdgcn_mfma_f32_16x16x32_bf16(ah1, bl, acc[1][nt], 0, 0, 0);
        }
        __syncthreads();   // drains stage(kc+1) + A prefetch; flips buffers
    }

#pragma unroll
    for (int mi = 0; mi < 2; mi++) {
        long gr0 = rowBase + wave * 32 + mi * 16 + quad * 4;
#pragma unroll
        for (int nt = 0; nt < NT; nt++) {
            f32x4 d = acc[mi][nt];
#pragma unroll
            for (int i = 0; i < 4; i++) {
                long gr = gr0 + i;
                if (gr < n) out[gr * NCOL + nt * 16 + r16] =
                    __float2half(d[i] * dinv[gr]);
            }
        }
    }
}

// ---------------- fp16 gather accumulate helpers ----------------

__device__ __forceinline__ void acc8(float* a, uint4 raw, float w) {
    __half2* hp = (__half2*)&raw;
    float2 f0 = __half22float2(hp[0]);
    float2 f1 = __half22float2(hp[1]);
    float2 f2 = __half22float2(hp[2]);
    float2 f3 = __half22float2(hp[3]);
    a[0] += w * f0.x; a[1] += w * f0.y; a[2] += w * f1.x; a[3] += w * f1.y;
    a[4] += w * f2.x; a[5] += w * f2.y; a[6] += w * f3.x; a[7] += w * f3.y;
}

__device__ __forceinline__ void acc4h(float* a, uint2 raw, float w) {
    __half2* hp = (__half2*)&raw;
    float2 f0 = __half22float2(hp[0]);
    float2 f1 = __half22float2(hp[1]);
    a[0] += w * f0.x; a[1] += w * f0.y; a[2] += w * f1.x; a[3] += w * f1.y;
}

// ---------------- aggregation layer 1 (D=128 fp16 in, fp32 out, +bias, relu) ----
// h' rows are pre-scaled by dinv[src]; edge weight is raw w; final scale dinv[node].

__global__ __launch_bounds__(256) void agg1_kernel(const __half* __restrict__ h,
        const float* __restrict__ dinv, const int* __restrict__ offsets,
        const int2* __restrict__ csc, const float* __restrict__ b,
        float* __restrict__ out, int n) {
    int t = threadIdx.x;
    int lane = t & 63;
    int strm = lane >> 4;            // 0..3
    int li = lane & 15;              // half8 index in row (16*8 = 128 dims)
    int node = blockIdx.x * 4 + (t >> 6);
    if (node >= n) return;

    float a0[8] = {0,0,0,0,0,0,0,0};
    float a1[8] = {0,0,0,0,0,0,0,0};
    int s = offsets[node], e = offsets[node + 1];

    if (strm == 0) {                 // self-loop: weight 1 * h'[node]
        uint4 raw = ((const uint4*)(h + (long)node * HID_DIM))[li];
        acc8(a0, raw, 1.0f);
    }

    int p = s + strm;
    for (; p + 4 < e; p += 8) {
        int2 e0 = csc[p], e1 = csc[p + 4];
        uint4 r0 = ((const uint4*)(h + (long)e0.x * HID_DIM))[li];
        uint4 r1 = ((const uint4*)(h + (long)e1.x * HID_DIM))[li];
        acc8(a0, r0, __int_as_float(e0.y));
        acc8(a1, r1, __int_as_float(e1.y));
    }
    if (p < e) {
        int2 e0 = csc[p];
        uint4 r0 = ((const uint4*)(h + (long)e0.x * HID_DIM))[li];
        acc8(a0, r0, __int_as_float(e0.y));
    }
#pragma unroll
    for (int j = 0; j < 8; j++) a0[j] += a1[j];
#pragma unroll
    for (int j = 0; j < 8; j++) a0[j] += __shfl_down(a0[j], 32);
#pragma unroll
    for (int j = 0; j < 8; j++) a0[j] += __shfl_down(a0[j], 16);
    if (strm == 0) {
        float di = dinv[node];
        float4 bv0 = ((const float4*)b)[li * 2];
        float4 bv1 = ((const float4*)b)[li * 2 + 1];
        float4 o0 = make_float4(fmaxf(di * a0[0] + bv0.x, 0.f), fmaxf(di * a0[1] + bv0.y, 0.f),
                                fmaxf(di * a0[2] + bv0.z, 0.f), fmaxf(di * a0[3] + bv0.w, 0.f));
        float4 o1 = make_float4(fmaxf(di * a0[4] + bv1.x, 0.f), fmaxf(di * a0[5] + bv1.y, 0.f),
                                fmaxf(di * a0[6] + bv1.z, 0.f), fmaxf(di * a0[7] + bv1.w, 0.f));
        float4* dst = (float4*)(out + (long)node * HID_DIM);
        dst[li * 2] = o0;
        dst[li * 2 + 1] = o1;
    }
}

// ---------------- aggregation layer 2 (D=64 fp16 in, fp32 out, +bias) ----------

__global__ __launch_bounds__(256) void agg2_kernel(const __half* __restrict__ h,
        const float* __restrict__ dinv, const int* __restrict__ offsets,
        const int2* __restrict__ csc, const float* __restrict__ b,
        float* __restrict__ out, int n) {
    int t = threadIdx.x;
    int lane = t & 63;
    int strm = lane >> 4;            // 0..3
    int li = lane & 15;              // half4 index in row (16*4 = 64 dims)
    int node = blockIdx.x * 4 + (t >> 6);
    if (node >= n) return;

    float a0[4] = {0,0,0,0};
    float a1[4] = {0,0,0,0};
    int s = offsets[node], e = offsets[node + 1];

    if (strm == 0) {
        uint2 raw = ((const uint2*)(h + (long)node * OUT_DIM))[li];
        acc4h(a0, raw, 1.0f);
    }

    int p = s + strm;
    for (; p + 4 < e; p += 8) {
        int2 e0 = csc[p], e1 = csc[p + 4];
        uint2 r0 = ((const uint2*)(h + (long)e0.x * OUT_DIM))[li];
        uint2 r1 = ((const uint2*)(h + (long)e1.x * OUT_DIM))[li];
        acc4h(a0, r0, __int_as_float(e0.y));
        acc4h(a1, r1, __int_as_float(e1.y));
    }
    if (p < e) {
        int2 e0 = csc[p];
        uint2 r0 = ((const uint2*)(h + (long)e0.x * OUT_DIM))[li];
        acc4h(a0, r0, __int_as_float(e0.y));
    }
#pragma unroll
    for (int j = 0; j < 4; j++) a0[j] += a1[j];
#pragma unroll
    for (int j = 0; j < 4; j++) a0[j] += __shfl_down(a0[j], 32);
#pragma unroll
    for (int j = 0; j < 4; j++) a0[j] += __shfl_down(a0[j], 16);
    if (strm == 0) {
        float di = dinv[node];
        float4 bv = ((const float4*)b)[li];
        ((float4*)(out + (long)node * OUT_DIM))[li] =
            make_float4(di * a0[0] + bv.x, di * a0[1] + bv.y,
                        di * a0[2] + bv.z, di * a0[3] + bv.w);
    }
}

// ---------------- launch ----------------

extern "C" void kernel_launch(void* const* d_in, const int* in_sizes, int n_in,
                              void* d_out, int out_size, void* d_ws, size_t ws_size,
                              hipStream_t stream) {
    const float* x  = (const float*)d_in[0];
    const int*   ei = (const int*)d_in[1];
    const float* w  = (const float*)d_in[2];
    const float* W1 = (const float*)d_in[3];
    const float* b1 = (const float*)d_in[4];
    const float* W2 = (const float*)d_in[5];
    const float* b2 = (const float*)d_in[6];
    float* out = (float*)d_out;

    int N = in_sizes[0] / IN_DIM;       // 100000
    int E = in_sizes[2];                // 1600000
    const int* row = ei;
    const int* col = ei + E;

    char* base = (char*)d_ws;
    size_t off = 0;
    auto alloc = [&](size_t bytes) -> void* {
        void* p = base + off;
        off += (bytes + 255) & ~(size_t)255;
        return p;
    };
    unsigned long long* packed = (unsigned long long*)alloc((size_t)N * 8);
    float* dinv     = (float*)alloc((size_t)N * 4);
    int*   cnt      = (int*)  alloc((size_t)N * 4);
    int*   offsets  = (int*)  alloc((size_t)(N + 1) * 4);
    int*   arr      = (int*)  alloc((size_t)E * 4);
    int*   bsum     = (int*)  alloc((size_t)1024 * 4);
    int2*  csc      = (int2*) alloc((size_t)E * 8);
    __half* h       = (__half*)alloc((size_t)N * HID_DIM * 2);  // fp16; reused for h2
    float* hagg     = (float*)alloc((size_t)N * HID_DIM * 4);
    unsigned short* wt1h = (unsigned short*)alloc((size_t)IN_DIM * HID_DIM * 2);
    unsigned short* wt1l = (unsigned short*)alloc((size_t)IN_DIM * HID_DIM * 2);
    unsigned short* wt2h = (unsigned short*)alloc((size_t)HID_DIM * OUT_DIM * 2);
    unsigned short* wt2l = (unsigned short*)alloc((size_t)HID_DIM * OUT_DIM * 2);

    int gN = (N + 255) / 256;
    int gE = (E + 255) / 256;
    int gGemm = (N + 127) / 128;
    int gAgg = (N + 3) / 4;
    int nbScan = (N + 1023) / 1024;

    wsplit_kernel<<<(IN_DIM * HID_DIM + 255) / 256, 256, 0, stream>>>(
        W1, wt1h, wt1l, IN_DIM, HID_DIM);
    wsplit_kernel<<<(HID_DIM * OUT_DIM + 255) / 256, 256, 0, stream>>>(
        W2, wt2h, wt2l, HID_DIM, OUT_DIM);
    init_kernel<<<gN, 256, 0, stream>>>(packed, N);
    deg_cnt_kernel<<<gE, 256, 0, stream>>>(col, w, packed, arr, E);
    dinv_kernel<<<gN, 256, 0, stream>>>(packed, dinv, cnt, N);
    scan1_kernel<<<nbScan, 256, 0, stream>>>(cnt, bsum, N);
    scan2_kernel<<<1, 1024, 0, stream>>>(bsum, offsets + N, nbScan);
    scan3_kernel<<<nbScan, 256, 0, stream>>>(cnt, bsum, offsets, N);
    fill_csc_kernel<<<gE, 256, 0, stream>>>(row, col, w, offsets, arr, csc, E);
    gemm_mfma_kernel<IN_DIM, HID_DIM><<<gGemm, 256, 0, stream>>>(x, wt1h, wt1l, dinv, h, N);
    agg1_kernel<<<gAgg, 256, 0, stream>>>(h, dinv, offsets, csc, b1, hagg, N);
    gemm_mfma_kernel<HID_DIM, OUT_DIM><<<gGemm, 256, 0, stream>>>(hagg, wt2h, wt2l, dinv, h, N);
    agg2_kernel<<<gAgg, 256, 0, stream>>>(h, dinv, offsets, csc, b2, out, N);
}

// Round 3
// 470.640 us; speedup vs baseline: 1.0997x; 1.0216x over previous
//
#include <hip/hip_runtime.h>
#include <hip/hip_fp16.h>
#include <hip/hip_bf16.h>

#define IN_DIM 256
#define HID_DIM 128
#define OUT_DIM 64

typedef short s8v __attribute__((ext_vector_type(8)));
typedef float f32x4 __attribute__((ext_vector_type(4)));

// ---------------- bf16 split helpers ----------------

__device__ __forceinline__ unsigned short bf16_rne(float f) {
    unsigned int u = __float_as_uint(f);
    u += 0x7FFFu + ((u >> 16) & 1u);
    return (unsigned short)(u >> 16);
}
__device__ __forceinline__ float bfbits_to_f(unsigned short h) {
    return __uint_as_float(((unsigned int)h) << 16);
}

// 8 consecutive floats -> hi/lo bf16 fragments via v_cvt_pk_bf16_f32
// (~3 VALU ops/elem vs ~10 for the manual RNE bit-trick; same RNE rounding).
__device__ __forceinline__ void cvt_split8(float4 f0, float4 f1, s8v& hi, s8v& lo) {
    float fv[8] = {f0.x, f0.y, f0.z, f0.w, f1.x, f1.y, f1.z, f1.w};
    unsigned int hw[4], lw[4];
#pragma unroll
    for (int i = 0; i < 4; i++) {
        __hip_bfloat162 hh = __float22bfloat162_rn(make_float2(fv[2*i], fv[2*i+1]));
        unsigned int hb = *(unsigned int*)&hh;
        float r0 = __uint_as_float(hb << 16);
        float r1 = __uint_as_float(hb & 0xffff0000u);
        __hip_bfloat162 ll = __float22bfloat162_rn(
            make_float2(fv[2*i] - r0, fv[2*i+1] - r1));
        hw[i] = hb;
        lw[i] = *(unsigned int*)&ll;
    }
    hi = *(s8v*)hw;
    lo = *(s8v*)lw;
}

__global__ __launch_bounds__(256) void wsplit_kernel(const float* __restrict__ W,
        unsigned short* __restrict__ wth, unsigned short* __restrict__ wtl,
        int K, int NCOL) {
    int idx = blockIdx.x * 256 + threadIdx.x;
    if (idx < K * NCOL) {
        int k = idx / NCOL, nn = idx % NCOL;
        float f = W[idx];
        unsigned short h = bf16_rne(f);
        unsigned short l = bf16_rne(f - bfbits_to_f(h));
        wth[nn * K + k] = h;
        wtl[nn * K + k] = l;
    }
}

// ---------------- preprocessing ----------------
// packed[i]: bits [63:40] = edge count, bits [39:0] = fixed-point (2^-24) sum of w.

#define FPSCALE 16777216.0f
#define FPMASK  ((1ULL << 40) - 1)

__global__ __launch_bounds__(256) void init_kernel(unsigned long long* packed, int n) {
    int i = blockIdx.x * 256 + threadIdx.x;
    if (i < n) packed[i] = (1ULL << 24);      // deg = 1.0 (self-loop), cnt = 0
}

// One u64 atomic per edge; the RETURN VALUE's cnt field is this edge's
// arrival index at its destination -> deterministic CSC slot later (no 2nd atomic).
__global__ __launch_bounds__(256) void deg_cnt_kernel(const int* __restrict__ col,
        const float* __restrict__ w, unsigned long long* packed,
        int* __restrict__ arr, int e) {
    int i = blockIdx.x * 256 + threadIdx.x;
    if (i < e) {
        unsigned long long v = (1ULL << 40) |
            (unsigned long long)(w[i] * FPSCALE + 0.5f);
        unsigned long long old = atomicAdd(&packed[col[i]], v);
        arr[i] = (int)(old >> 40);
    }
}

__global__ __launch_bounds__(256) void dinv_kernel(const unsigned long long* __restrict__ packed,
        float* __restrict__ dinv, int* __restrict__ cnt, int n) {
    int i = blockIdx.x * 256 + threadIdx.x;
    if (i < n) {
        unsigned long long p = packed[i];
        float d = (float)(p & FPMASK) * (1.0f / FPSCALE);
        dinv[i] = d > 0.0f ? rsqrtf(d) : 0.0f;
        cnt[i] = (int)(p >> 40);
    }
}

// ---- hierarchical exclusive scan ----

__global__ __launch_bounds__(256) void scan1_kernel(const int* __restrict__ cnt,
        int* __restrict__ bsum, int n) {
    int t = threadIdx.x;
    int base = blockIdx.x * 1024 + t * 4;
    int s = 0;
    if (base + 3 < n) {
        int4 v = *(const int4*)(cnt + base);
        s = v.x + v.y + v.z + v.w;
    } else {
        for (int i = 0; i < 4; i++) if (base + i < n) s += cnt[base + i];
    }
    __shared__ int sm[256];
    sm[t] = s;
    __syncthreads();
    for (int d = 1; d < 256; d <<= 1) {
        int v = (t >= d) ? sm[t - d] : 0;
        __syncthreads();
        sm[t] += v;
        __syncthreads();
    }
    if (t == 255) bsum[blockIdx.x] = sm[255];
}

__global__ __launch_bounds__(1024) void scan2_kernel(int* bsum, int* total_out, int nb) {
    __shared__ int sm[1024];
    int t = threadIdx.x;
    int v = (t < nb) ? bsum[t] : 0;
    sm[t] = v;
    __syncthreads();
    for (int d = 1; d < 1024; d <<= 1) {
        int u = (t >= d) ? sm[t - d] : 0;
        __syncthreads();
        sm[t] += u;
        __syncthreads();
    }
    int ex = (t == 0) ? 0 : sm[t - 1];
    if (t < nb) bsum[t] = ex;
    if (t == nb - 1) *total_out = sm[t];
}

__global__ __launch_bounds__(256) void scan3_kernel(const int* __restrict__ cnt,
        const int* __restrict__ bsum, int* __restrict__ offsets, int n) {
    int t = threadIdx.x;
    int base = blockIdx.x * 1024 + t * 4;
    int a[4] = {0, 0, 0, 0};
    if (base + 3 < n) {
        int4 v = *(const int4*)(cnt + base);
        a[0] = v.x; a[1] = v.y; a[2] = v.z; a[3] = v.w;
    } else {
        for (int i = 0; i < 4; i++) if (base + i < n) a[i] = cnt[base + i];
    }
    int s = a[0] + a[1] + a[2] + a[3];
    __shared__ int sm[256];
    sm[t] = s;
    __syncthreads();
    for (int d = 1; d < 256; d <<= 1) {
        int u = (t >= d) ? sm[t - d] : 0;
        __syncthreads();
        sm[t] += u;
        __syncthreads();
    }
    int pre = bsum[blockIdx.x] + ((t == 0) ? 0 : sm[t - 1]);
    int o0 = pre, o1 = o0 + a[0], o2 = o1 + a[1], o3 = o2 + a[2];
    if (base + 3 < n) {
        *(int4*)(offsets + base) = make_int4(o0, o1, o2, o3);
    } else {
        int o[4] = {o0, o1, o2, o3};
        for (int i = 0; i < 4; i++) if (base + i < n) offsets[base + i] = o[i];
    }
}

// CSC entry: int2{ src_row, float_bits(w) } — dinv folded elsewhere.
// No atomic: slot = offsets[col] + arrival index from deg_cnt.

__global__ __launch_bounds__(256) void fill_csc_kernel(const int* __restrict__ row,
        const int* __restrict__ col, const float* __restrict__ w,
        const int* __restrict__ offsets, const int* __restrict__ arr,
        int2* __restrict__ csc, int e) {
    int i = blockIdx.x * 256 + threadIdx.x;
    if (i < e) {
        int c = col[i];
        int p = offsets[c] + arr[i];
        csc[p] = make_int2(row[i], __float_as_int(w[i]));
    }
}

// ---------------- MFMA split-bf16 GEMM (fp16 output, row-scaled by dinv) ------
// r2 post-mortem: bottleneck = B-operand LDS traffic (bytes/MFMA depends only
// on M-rows per wave). Fixes here:
//  * M=64 rows/wave (2-wave 128-thread blocks, 128-row tile): same 16
//    ds_read_b128 per chunk now feed 96 MFMAs -> LDS ~1 cy/MFMA vs MFMA
//    1.25 cy-CU (balance point).
//  * XOR slot swizzle (both-sides): phys_slot = quad ^ ((row>>1)&3). Write
//    side stays HW-linear (global_load_lds lane*16B) with the INVERSE applied
//    to the per-lane GLOBAL source; read applies it to the ds_read addr.
//    Within a 16-lane quarter each 16B bank-group gets exactly 2 lanes (min)
//    -> kills the 8-way conflict of the naive [NCOL][32] layout.
//  * A stays global->reg (zero cross-lane reuse; LDS would be pure overhead),
//    one-chunk register prefetch; split via v_cvt_pk_bf16_f32.

template<int K, int NCOL>
__global__ __launch_bounds__(128, 2) void gemm_mfma_kernel(
        const float* __restrict__ x, const unsigned short* __restrict__ wth,
        const unsigned short* __restrict__ wtl, const float* __restrict__ dinv,
        __half* __restrict__ out, int n) {
    constexpr int NT = NCOL / 16;          // 16-col tiles
    constexpr int NCH = K / 32;            // K chunks
    constexpr int NS = NCOL / 16;          // 16-row B segments per chunk

    __shared__ unsigned short sBh[2][NCOL][32];
    __shared__ unsigned short sBl[2][NCOL][32];

    int t = threadIdx.x;
    int wave = t >> 6, lane = t & 63, quad = lane >> 4, r16 = lane & 15;
    long rowBase = (long)blockIdx.x * 128 + wave * 64;

    f32x4 acc[4][NT];
#pragma unroll
    for (int mi = 0; mi < 4; mi++)
#pragma unroll
        for (int nt = 0; nt < NT; nt++) acc[mi][nt] = (f32x4)0.0f;

    const float* pa[4];
#pragma unroll
    for (int mi = 0; mi < 4; mi++) {
        long r = rowBase + mi * 16 + r16;
        if (r > n - 1) r = n - 1;
        pa[mi] = x + r * K + quad * 8;
    }

    // staging: lane l writes phys (row=l>>2, slot=l&3) of its 16-row segment;
    // it must fetch logical slot = phys ^ sw(row), sw(row) = (row>>1)&3.
    int srcSlot = ((lane & 3) ^ ((lane >> 3) & 3)) * 8;   // in shorts
    int lrow = lane >> 2;

    auto stage = [&](int buf, int kc) {
#pragma unroll
        for (int j = 0; j < NS / 2; j++) {
            int s = wave + 2 * j;                 // 16-row segment id
            int r = s * 16 + lrow;                // B row (= output col)
            const unsigned short* gh = wth + (long)r * K + kc * 32 + srcSlot;
            const unsigned short* gl = wtl + (long)r * K + kc * 32 + srcSlot;
            __builtin_amdgcn_global_load_lds(
                (const __attribute__((address_space(1))) unsigned int*)gh,
                (__attribute__((address_space(3))) unsigned int*)&sBh[buf][s * 16][0],
                16, 0, 0);
            __builtin_amdgcn_global_load_lds(
                (const __attribute__((address_space(1))) unsigned int*)gl,
                (__attribute__((address_space(3))) unsigned int*)&sBl[buf][s * 16][0],
                16, 0, 0);
        }
    };

    // prologue: stage chunk 0, prefetch A chunk 0
    stage(0, 0);
    float4 a[8];
#pragma unroll
    for (int mi = 0; mi < 4; mi++) {
        a[2 * mi]     = *(const float4*)(pa[mi]);
        a[2 * mi + 1] = *(const float4*)(pa[mi] + 4);
    }
    __syncthreads();

    int rdSlot = (r16 >> 1) & 3;    // read-side swizzle component

    for (int kc = 0; kc < NCH; kc++) {
        int buf = kc & 1;
        if (kc + 1 < NCH) stage(buf ^ 1, kc + 1);   // B prefetch over MFMA

        s8v ah[4], al[4];
#pragma unroll
        for (int mi = 0; mi < 4; mi++)
            cvt_split8(a[2 * mi], a[2 * mi + 1], ah[mi], al[mi]);
        if (kc + 1 < NCH) {                          // A register prefetch
#pragma unroll
            for (int mi = 0; mi < 4; mi++) {
                const float* q = pa[mi] + (kc + 1) * 32;
                a[2 * mi]     = *(const float4*)(q);
                a[2 * mi + 1] = *(const float4*)(q + 4);
            }
        }
#pragma unroll
        for (int nt = 0; nt < NT; nt++) {
            int sl = (quad ^ rdSlot) * 8;
            s8v bh = *(const s8v*)&sBh[buf][nt * 16 + r16][sl];
            s8v bl = *(const s8v*)&sBl[buf][nt * 16 + r16][sl];
#pragma unroll
            for (int mi = 0; mi < 4; mi++) {
                acc[mi][nt] = __builtin_amdgcn_mfma_f32_16x16x32_bf16(ah[mi], bh, acc[mi][nt], 0, 0, 0);
                acc[mi][nt] = __builtin_amdgcn_mfma_f32_16x16x32_bf16(al[mi], bh, acc[mi][nt], 0, 0, 0);
                acc[mi][nt] = __builtin_amdgcn_mfma_f32_16x16x32_bf16(ah[mi], bl, acc[mi][nt], 0, 0, 0);
            }
        }
        __syncthreads();   // drains stage(kc+1) + flips buffers
    }

#pragma unroll
    for (int mi = 0; mi < 4; mi++) {
        long gr0 = rowBase + mi * 16 + quad * 4;
        float dv[4];
#pragma unroll
        for (int i = 0; i < 4; i++)
            dv[i] = (gr0 + i < n) ? dinv[gr0 + i] : 0.0f;
#pragma unroll
        for (int nt = 0; nt < NT; nt++) {
            f32x4 d = acc[mi][nt];
#pragma unroll
            for (int i = 0; i < 4; i++) {
                long gr = gr0 + i;
                if (gr < n) out[gr * NCOL + nt * 16 + r16] =
                    __float2half(d[i] * dv[i]);
            }
        }
    }
}

// ---------------- fp16 gather accumulate helpers ----------------

__device__ __forceinline__ void acc8(float* a, uint4 raw, float w) {
    __half2* hp = (__half2*)&raw;
    float2 f0 = __half22float2(hp[0]);
    float2 f1 = __half22float2(hp[1]);
    float2 f2 = __half22float2(hp[2]);
    float2 f3 = __half22float2(hp[3]);
    a[0] += w * f0.x; a[1] += w * f0.y; a[2] += w * f1.x; a[3] += w * f1.y;
    a[4] += w * f2.x; a[5] += w * f2.y; a[6] += w * f3.x; a[7] += w * f3.y;
}

__device__ __forceinline__ void acc4h(float* a, uint2 raw, float w) {
    __half2* hp = (__half2*)&raw;
    float2 f0 = __half22float2(hp[0]);
    float2 f1 = __half22float2(hp[1]);
    a[0] += w * f0.x; a[1] += w * f0.y; a[2] += w * f1.x; a[3] += w * f1.y;
}

// ---------------- aggregation layer 1 (D=128 fp16 in, fp32 out, +bias, relu) ----
// h' rows are pre-scaled by dinv[src]; edge weight is raw w; final scale dinv[node].

__global__ __launch_bounds__(256) void agg1_kernel(const __half* __restrict__ h,
        const float* __restrict__ dinv, const int* __restrict__ offsets,
        const int2* __restrict__ csc, const float* __restrict__ b,
        float* __restrict__ out, int n) {
    int t = threadIdx.x;
    int lane = t & 63;
    int strm = lane >> 4;            // 0..3
    int li = lane & 15;              // half8 index in row (16*8 = 128 dims)
    int node = blockIdx.x * 4 + (t >> 6);
    if (node >= n) return;

    float a0[8] = {0,0,0,0,0,0,0,0};
    float a1[8] = {0,0,0,0,0,0,0,0};
    int s = offsets[node], e = offsets[node + 1];

    if (strm == 0) {                 // self-loop: weight 1 * h'[node]
        uint4 raw = ((const uint4*)(h + (long)node * HID_DIM))[li];
        acc8(a0, raw, 1.0f);
    }

    int p = s + strm;
    for (; p + 4 < e; p += 8) {
        int2 e0 = csc[p], e1 = csc[p + 4];
        uint4 r0 = ((const uint4*)(h + (long)e0.x * HID_DIM))[li];
        uint4 r1 = ((const uint4*)(h + (long)e1.x * HID_DIM))[li];
        acc8(a0, r0, __int_as_float(e0.y));
        acc8(a1, r1, __int_as_float(e1.y));
    }
    if (p < e) {
        int2 e0 = csc[p];
        uint4 r0 = ((const uint4*)(h + (long)e0.x * HID_DIM))[li];
        acc8(a0, r0, __int_as_float(e0.y));
    }
#pragma unroll
    for (int j = 0; j < 8; j++) a0[j] += a1[j];
#pragma unroll
    for (int j = 0; j < 8; j++) a0[j] += __shfl_down(a0[j], 32);
#pragma unroll
    for (int j = 0; j < 8; j++) a0[j] += __shfl_down(a0[j], 16);
    if (strm == 0) {
        float di = dinv[node];
        float4 bv0 = ((const float4*)b)[li * 2];
        float4 bv1 = ((const float4*)b)[li * 2 + 1];
        float4 o0 = make_float4(fmaxf(di * a0[0] + bv0.x, 0.f), fmaxf(di * a0[1] + bv0.y, 0.f),
                                fmaxf(di * a0[2] + bv0.z, 0.f), fmaxf(di * a0[3] + bv0.w, 0.f));
        float4 o1 = make_float4(fmaxf(di * a0[4] + bv1.x, 0.f), fmaxf(di * a0[5] + bv1.y, 0.f),
                                fmaxf(di * a0[6] + bv1.z, 0.f), fmaxf(di * a0[7] + bv1.w, 0.f));
        float4* dst = (float4*)(out + (long)node * HID_DIM);
        dst[li * 2] = o0;
        dst[li * 2 + 1] = o1;
    }
}

// ---------------- aggregation layer 2 (D=64 fp16 in, fp32 out, +bias) ----------

__global__ __launch_bounds__(256) void agg2_kernel(const __half* __restrict__ h,
        const float* __restrict__ dinv, const int* __restrict__ offsets,
        const int2* __restrict__ csc, const float* __restrict__ b,
        float* __restrict__ out, int n) {
    int t = threadIdx.x;
    int lane = t & 63;
    int strm = lane >> 4;            // 0..3
    int li = lane & 15;              // half4 index in row (16*4 = 64 dims)
    int node = blockIdx.x * 4 + (t >> 6);
    if (node >= n) return;

    float a0[4] = {0,0,0,0};
    float a1[4] = {0,0,0,0};
    int s = offsets[node], e = offsets[node + 1];

    if (strm == 0) {
        uint2 raw = ((const uint2*)(h + (long)node * OUT_DIM))[li];
        acc4h(a0, raw, 1.0f);
    }

    int p = s + strm;
    for (; p + 4 < e; p += 8) {
        int2 e0 = csc[p], e1 = csc[p + 4];
        uint2 r0 = ((const uint2*)(h + (long)e0.x * OUT_DIM))[li];
        uint2 r1 = ((const uint2*)(h + (long)e1.x * OUT_DIM))[li];
        acc4h(a0, r0, __int_as_float(e0.y));
        acc4h(a1, r1, __int_as_float(e1.y));
    }
    if (p < e) {
        int2 e0 = csc[p];
        uint2 r0 = ((const uint2*)(h + (long)e0.x * OUT_DIM))[li];
        acc4h(a0, r0, __int_as_float(e0.y));
    }
#pragma unroll
    for (int j = 0; j < 4; j++) a0[j] += a1[j];
#pragma unroll
    for (int j = 0; j < 4; j++) a0[j] += __shfl_down(a0[j], 32);
#pragma unroll
    for (int j = 0; j < 4; j++) a0[j] += __shfl_down(a0[j], 16);
    if (strm == 0) {
        float di = dinv[node];
        float4 bv = ((const float4*)b)[li];
        ((float4*)(out + (long)node * OUT_DIM))[li] =
            make_float4(di * a0[0] + bv.x, di * a0[1] + bv.y,
                        di * a0[2] + bv.z, di * a0[3] + bv.w);
    }
}

// ---------------- launch ----------------

extern "C" void kernel_launch(void* const* d_in, const int* in_sizes, int n_in,
                              void* d_out, int out_size, void* d_ws, size_t ws_size,
                              hipStream_t stream) {
    const float* x  = (const float*)d_in[0];
    const int*   ei = (const int*)d_in[1];
    const float* w  = (const float*)d_in[2];
    const float* W1 = (const float*)d_in[3];
    const float* b1 = (const float*)d_in[4];
    const float* W2 = (const float*)d_in[5];
    const float* b2 = (const float*)d_in[6];
    float* out = (float*)d_out;

    int N = in_sizes[0] / IN_DIM;       // 100000
    int E = in_sizes[2];                // 1600000
    const int* row = ei;
    const int* col = ei + E;

    char* base = (char*)d_ws;
    size_t off = 0;
    auto alloc = [&](size_t bytes) -> void* {
        void* p = base + off;
        off += (bytes + 255) & ~(size_t)255;
        return p;
    };
    unsigned long long* packed = (unsigned long long*)alloc((size_t)N * 8);
    float* dinv     = (float*)alloc((size_t)N * 4);
    int*   cnt      = (int*)  alloc((size_t)N * 4);
    int*   offsets  = (int*)  alloc((size_t)(N + 1) * 4);
    int*   arr      = (int*)  alloc((size_t)E * 4);
    int*   bsum     = (int*)  alloc((size_t)1024 * 4);
    int2*  csc      = (int2*) alloc((size_t)E * 8);
    __half* h       = (__half*)alloc((size_t)N * HID_DIM * 2);  // fp16; reused for h2
    float* hagg     = (float*)alloc((size_t)N * HID_DIM * 4);
    unsigned short* wt1h = (unsigned short*)alloc((size_t)IN_DIM * HID_DIM * 2);
    unsigned short* wt1l = (unsigned short*)alloc((size_t)IN_DIM * HID_DIM * 2);
    unsigned short* wt2h = (unsigned short*)alloc((size_t)HID_DIM * OUT_DIM * 2);
    unsigned short* wt2l = (unsigned short*)alloc((size_t)HID_DIM * OUT_DIM * 2);

    int gN = (N + 255) / 256;
    int gE = (E + 255) / 256;
    int gGemm = (N + 127) / 128;     // 128-row tiles, 128-thread blocks
    int gAgg = (N + 3) / 4;
    int nbScan = (N + 1023) / 1024;

    wsplit_kernel<<<(IN_DIM * HID_DIM + 255) / 256, 256, 0, stream>>>(
        W1, wt1h, wt1l, IN_DIM, HID_DIM);
    wsplit_kernel<<<(HID_DIM * OUT_DIM + 255) / 256, 256, 0, stream>>>(
        W2, wt2h, wt2l, HID_DIM, OUT_DIM);
    init_kernel<<<gN, 256, 0, stream>>>(packed, N);
    deg_cnt_kernel<<<gE, 256, 0, stream>>>(col, w, packed, arr, E);
    dinv_kernel<<<gN, 256, 0, stream>>>(packed, dinv, cnt, N);
    scan1_kernel<<<nbScan, 256, 0, stream>>>(cnt, bsum, N);
    scan2_kernel<<<1, 1024, 0, stream>>>(bsum, offsets + N, nbScan);
    scan3_kernel<<<nbScan, 256, 0, stream>>>(cnt, bsum, offsets, N);
    fill_csc_kernel<<<gE, 256, 0, stream>>>(row, col, w, offsets, arr, csc, E);
    gemm_mfma_kernel<IN_DIM, HID_DIM><<<gGemm, 128, 0, stream>>>(x, wt1h, wt1l, dinv, h, N);
    agg1_kernel<<<gAgg, 256, 0, stream>>>(h, dinv, offsets, csc, b1, hagg, N);
    gemm_mfma_kernel<HID_DIM, OUT_DIM><<<gGemm, 128, 0, stream>>>(hagg, wt2h, wt2l, dinv, h, N);
    agg2_kernel<<<gAgg, 256, 0, stream>>>(h, dinv, offsets, csc, b2, out, N);
}

// Round 4
// 417.856 us; speedup vs baseline: 1.2386x; 1.1263x over previous
//
#include <hip/hip_runtime.h>
#include <hip/hip_fp16.h>
#include <hip/hip_bf16.h>

#define IN_DIM 256
#define HID_DIM 128
#define OUT_DIM 64

typedef short s8v __attribute__((ext_vector_type(8)));
typedef float f32x4 __attribute__((ext_vector_type(4)));

// ---------------- bf16 split helpers ----------------

__device__ __forceinline__ unsigned short bf16_rne(float f) {
    unsigned int u = __float_as_uint(f);
    u += 0x7FFFu + ((u >> 16) & 1u);
    return (unsigned short)(u >> 16);
}
__device__ __forceinline__ float bfbits_to_f(unsigned short h) {
    return __uint_as_float(((unsigned int)h) << 16);
}

// 8 consecutive floats -> hi/lo bf16 fragments via v_cvt_pk_bf16_f32
__device__ __forceinline__ void cvt_split8(float4 f0, float4 f1, s8v& hi, s8v& lo) {
    float fv[8] = {f0.x, f0.y, f0.z, f0.w, f1.x, f1.y, f1.z, f1.w};
    unsigned int hw[4], lw[4];
#pragma unroll
    for (int i = 0; i < 4; i++) {
        __hip_bfloat162 hh = __float22bfloat162_rn(make_float2(fv[2*i], fv[2*i+1]));
        unsigned int hb = *(unsigned int*)&hh;
        float r0 = __uint_as_float(hb << 16);
        float r1 = __uint_as_float(hb & 0xffff0000u);
        __hip_bfloat162 ll = __float22bfloat162_rn(
            make_float2(fv[2*i] - r0, fv[2*i+1] - r1));
        hw[i] = hb;
        lw[i] = *(unsigned int*)&ll;
    }
    hi = *(s8v*)hw;
    lo = *(s8v*)lw;
}

__global__ __launch_bounds__(256) void wsplit_kernel(const float* __restrict__ W,
        unsigned short* __restrict__ wth, unsigned short* __restrict__ wtl,
        int K, int NCOL) {
    int idx = blockIdx.x * 256 + threadIdx.x;
    if (idx < K * NCOL) {
        int k = idx / NCOL, nn = idx % NCOL;
        float f = W[idx];
        unsigned short h = bf16_rne(f);
        unsigned short l = bf16_rne(f - bfbits_to_f(h));
        wth[nn * K + k] = h;
        wtl[nn * K + k] = l;
    }
}

// ---------------- preprocessing ----------------
// packed[i]: bits [63:40] = edge count, bits [39:0] = fixed-point (2^-24) sum of w.

#define FPSCALE 16777216.0f
#define FPMASK  ((1ULL << 40) - 1)

__global__ __launch_bounds__(256) void init_kernel(unsigned long long* packed, int n) {
    int i = blockIdx.x * 256 + threadIdx.x;
    if (i < n) packed[i] = (1ULL << 24);      // deg = 1.0 (self-loop), cnt = 0
}

__global__ __launch_bounds__(256) void dinv_kernel(const unsigned long long* __restrict__ packed,
        float* __restrict__ dinv, int* __restrict__ cnt, int n) {
    int i = blockIdx.x * 256 + threadIdx.x;
    if (i < n) {
        unsigned long long p = packed[i];
        float d = (float)(p & FPMASK) * (1.0f / FPSCALE);
        dinv[i] = d > 0.0f ? rsqrtf(d) : 0.0f;
        cnt[i] = (int)(p >> 40);
    }
}

// ---- hierarchical exclusive scan ----

__global__ __launch_bounds__(256) void scan1_kernel(const int* __restrict__ cnt,
        int* __restrict__ bsum, int n) {
    int t = threadIdx.x;
    int base = blockIdx.x * 1024 + t * 4;
    int s = 0;
    if (base + 3 < n) {
        int4 v = *(const int4*)(cnt + base);
        s = v.x + v.y + v.z + v.w;
    } else {
        for (int i = 0; i < 4; i++) if (base + i < n) s += cnt[base + i];
    }
    __shared__ int sm[256];
    sm[t] = s;
    __syncthreads();
    for (int d = 1; d < 256; d <<= 1) {
        int v = (t >= d) ? sm[t - d] : 0;
        __syncthreads();
        sm[t] += v;
        __syncthreads();
    }
    if (t == 255) bsum[blockIdx.x] = sm[255];
}

__global__ __launch_bounds__(1024) void scan2_kernel(int* bsum, int* total_out, int nb) {
    __shared__ int sm[1024];
    int t = threadIdx.x;
    int v = (t < nb) ? bsum[t] : 0;
    sm[t] = v;
    __syncthreads();
    for (int d = 1; d < 1024; d <<= 1) {
        int u = (t >= d) ? sm[t - d] : 0;
        __syncthreads();
        sm[t] += u;
        __syncthreads();
    }
    int ex = (t == 0) ? 0 : sm[t - 1];
    if (t < nb) bsum[t] = ex;
    if (t == nb - 1) *total_out = sm[t];
}

__global__ __launch_bounds__(256) void scan3_kernel(const int* __restrict__ cnt,
        const int* __restrict__ bsum, int* __restrict__ offsets, int n) {
    int t = threadIdx.x;
    int base = blockIdx.x * 1024 + t * 4;
    int a[4] = {0, 0, 0, 0};
    if (base + 3 < n) {
        int4 v = *(const int4*)(cnt + base);
        a[0] = v.x; a[1] = v.y; a[2] = v.z; a[3] = v.w;
    } else {
        for (int i = 0; i < 4; i++) if (base + i < n) a[i] = cnt[base + i];
    }
    int s = a[0] + a[1] + a[2] + a[3];
    __shared__ int sm[256];
    sm[t] = s;
    __syncthreads();
    for (int d = 1; d < 256; d <<= 1) {
        int u = (t >= d) ? sm[t - d] : 0;
        __syncthreads();
        sm[t] += u;
        __syncthreads();
    }
    int pre = bsum[blockIdx.x] + ((t == 0) ? 0 : sm[t - 1]);
    int o0 = pre, o1 = o0 + a[0], o2 = o1 + a[1], o3 = o2 + a[2];
    if (base + 3 < n) {
        *(int4*)(offsets + base) = make_int4(o0, o1, o2, o3);
    } else {
        int o[4] = {o0, o1, o2, o3};
        for (int i = 0; i < 4; i++) if (base + i < n) offsets[base + i] = o[i];
    }
}

// CSC entry: int2{ src_row, float_bits(w * dinv[src]) }.
// No atomic: slot = offsets[col] + arrival index from the fused deg pass.
// dinv[src] is folded here so the GEMM no longer depends on dinv (enables
// fusing the deg atomics under GEMM1).

__global__ __launch_bounds__(256) void fill_csc_kernel(const int* __restrict__ row,
        const int* __restrict__ col, const float* __restrict__ w,
        const float* __restrict__ dinv,
        const int* __restrict__ offsets, const int* __restrict__ arr,
        int2* __restrict__ csc, int e) {
    int i = blockIdx.x * 256 + threadIdx.x;
    if (i < e) {
        int c = col[i];
        int r = row[i];
        int p = offsets[c] + arr[i];
        csc[p] = make_int2(r, __float_as_int(w[i] * dinv[r]));
    }
}

// ---------------- fused MFMA GEMM + deg/cnt atomics -------------------------
// Blocks [0, gemmBlocks): the r3 split-bf16 GEMM (M=64/wave, XOR-swizzled B
// staging via global_load_lds, A global->reg). Writes UNSCALED x@W in fp16.
// Blocks [gemmBlocks, ...): 1024 edges/block, one u64 atomicAdd per edge
// (deg-sum + count + arrival index). These waves idle on the device-scope
// atomic unit (~21 G/s, VALU ~1%, HBM ~10%) — the exact complement of the
// GEMM's MFMA/LDS profile, so the two roles overlap nearly for free (m114).

template<int K, int NCOL, bool DEG>
__global__ __launch_bounds__(128, 2) void gemm_deg_kernel(
        const float* __restrict__ x, const unsigned short* __restrict__ wth,
        const unsigned short* __restrict__ wtl,
        __half* __restrict__ out, int n, int gemmBlocks,
        const int* __restrict__ colIdx, const float* __restrict__ ew,
        unsigned long long* packed, int* __restrict__ arr, int eCount) {
    constexpr int NT = NCOL / 16;          // 16-col tiles
    constexpr int NCH = K / 32;            // K chunks
    constexpr int NS = NCOL / 16;          // 16-row B segments per chunk

    __shared__ unsigned short sBh[2][NCOL][32];
    __shared__ unsigned short sBl[2][NCOL][32];

    int t = threadIdx.x;

    if (DEG && (int)blockIdx.x >= gemmBlocks) {
        // ---- edge-atomic role ----
        long ebase = (long)((int)blockIdx.x - gemmBlocks) * 1024;
#pragma unroll
        for (int j = 0; j < 2; j++) {
            long i = ebase + j * 512 + t * 4;
            if (i + 3 < eCount) {
                int4 c4 = *(const int4*)(colIdx + i);
                float4 w4 = *(const float4*)(ew + i);
                unsigned long long o0 = atomicAdd(&packed[c4.x],
                    (1ULL << 40) | (unsigned long long)(w4.x * FPSCALE + 0.5f));
                unsigned long long o1 = atomicAdd(&packed[c4.y],
                    (1ULL << 40) | (unsigned long long)(w4.y * FPSCALE + 0.5f));
                unsigned long long o2 = atomicAdd(&packed[c4.z],
                    (1ULL << 40) | (unsigned long long)(w4.z * FPSCALE + 0.5f));
                unsigned long long o3 = atomicAdd(&packed[c4.w],
                    (1ULL << 40) | (unsigned long long)(w4.w * FPSCALE + 0.5f));
                *(int4*)(arr + i) = make_int4((int)(o0 >> 40), (int)(o1 >> 40),
                                              (int)(o2 >> 40), (int)(o3 >> 40));
            } else {
                for (int q = 0; q < 4; q++) {
                    long ii = i + q;
                    if (ii < eCount) {
                        unsigned long long v = (1ULL << 40) |
                            (unsigned long long)(ew[ii] * FPSCALE + 0.5f);
                        unsigned long long old = atomicAdd(&packed[colIdx[ii]], v);
                        arr[ii] = (int)(old >> 40);
                    }
                }
            }
        }
        return;
    }

    // ---- GEMM role ----
    int wave = t >> 6, lane = t & 63, quad = lane >> 4, r16 = lane & 15;
    long rowBase = (long)blockIdx.x * 128 + wave * 64;

    f32x4 acc[4][NT];
#pragma unroll
    for (int mi = 0; mi < 4; mi++)
#pragma unroll
        for (int nt = 0; nt < NT; nt++) acc[mi][nt] = (f32x4)0.0f;

    const float* pa[4];
#pragma unroll
    for (int mi = 0; mi < 4; mi++) {
        long r = rowBase + mi * 16 + r16;
        if (r > n - 1) r = n - 1;
        pa[mi] = x + r * K + quad * 8;
    }

    // staging: lane l writes phys (row=l>>2, slot=l&3); fetch logical slot =
    // phys ^ sw(row), sw(row)=(row>>1)&3  (both-sides XOR swizzle).
    int srcSlot = ((lane & 3) ^ ((lane >> 3) & 3)) * 8;   // in shorts
    int lrow = lane >> 2;

    auto stage = [&](int buf, int kc) {
#pragma unroll
        for (int j = 0; j < NS / 2; j++) {
            int s = wave + 2 * j;                 // 16-row segment id
            int r = s * 16 + lrow;                // B row (= output col)
            const unsigned short* gh = wth + (long)r * K + kc * 32 + srcSlot;
            const unsigned short* gl = wtl + (long)r * K + kc * 32 + srcSlot;
            __builtin_amdgcn_global_load_lds(
                (const __attribute__((address_space(1))) unsigned int*)gh,
                (__attribute__((address_space(3))) unsigned int*)&sBh[buf][s * 16][0],
                16, 0, 0);
            __builtin_amdgcn_global_load_lds(
                (const __attribute__((address_space(1))) unsigned int*)gl,
                (__attribute__((address_space(3))) unsigned int*)&sBl[buf][s * 16][0],
                16, 0, 0);
        }
    };

    // prologue: stage chunk 0, prefetch A chunk 0
    stage(0, 0);
    float4 a[8];
#pragma unroll
    for (int mi = 0; mi < 4; mi++) {
        a[2 * mi]     = *(const float4*)(pa[mi]);
        a[2 * mi + 1] = *(const float4*)(pa[mi] + 4);
    }
    __syncthreads();

    int rdSlot = (r16 >> 1) & 3;    // read-side swizzle component

    for (int kc = 0; kc < NCH; kc++) {
        int buf = kc & 1;
        if (kc + 1 < NCH) stage(buf ^ 1, kc + 1);   // B prefetch over MFMA

        s8v ah[4], al[4];
#pragma unroll
        for (int mi = 0; mi < 4; mi++)
            cvt_split8(a[2 * mi], a[2 * mi + 1], ah[mi], al[mi]);
        if (kc + 1 < NCH) {                          // A register prefetch
#pragma unroll
            for (int mi = 0; mi < 4; mi++) {
                const float* q = pa[mi] + (kc + 1) * 32;
                a[2 * mi]     = *(const float4*)(q);
                a[2 * mi + 1] = *(const float4*)(q + 4);
            }
        }
#pragma unroll
        for (int nt = 0; nt < NT; nt++) {
            int sl = (quad ^ rdSlot) * 8;
            s8v bh = *(const s8v*)&sBh[buf][nt * 16 + r16][sl];
            s8v bl = *(const s8v*)&sBl[buf][nt * 16 + r16][sl];
#pragma unroll
            for (int mi = 0; mi < 4; mi++) {
                acc[mi][nt] = __builtin_amdgcn_mfma_f32_16x16x32_bf16(ah[mi], bh, acc[mi][nt], 0, 0, 0);
                acc[mi][nt] = __builtin_amdgcn_mfma_f32_16x16x32_bf16(al[mi], bh, acc[mi][nt], 0, 0, 0);
                acc[mi][nt] = __builtin_amdgcn_mfma_f32_16x16x32_bf16(ah[mi], bl, acc[mi][nt], 0, 0, 0);
            }
        }
        __syncthreads();   // drains stage(kc+1) + flips buffers
    }

#pragma unroll
    for (int mi = 0; mi < 4; mi++) {
        long gr0 = rowBase + mi * 16 + quad * 4;
#pragma unroll
        for (int nt = 0; nt < NT; nt++) {
            f32x4 d = acc[mi][nt];
#pragma unroll
            for (int i = 0; i < 4; i++) {
                long gr = gr0 + i;
                if (gr < n) out[gr * NCOL + nt * 16 + r16] = __float2half(d[i]);
            }
        }
    }
}

// ---------------- fp16 gather accumulate helpers ----------------

__device__ __forceinline__ void acc8(float* a, uint4 raw, float w) {
    __half2* hp = (__half2*)&raw;
    float2 f0 = __half22float2(hp[0]);
    float2 f1 = __half22float2(hp[1]);
    float2 f2 = __half22float2(hp[2]);
    float2 f3 = __half22float2(hp[3]);
    a[0] += w * f0.x; a[1] += w * f0.y; a[2] += w * f1.x; a[3] += w * f1.y;
    a[4] += w * f2.x; a[5] += w * f2.y; a[6] += w * f3.x; a[7] += w * f3.y;
}

__device__ __forceinline__ void acc4h(float* a, uint2 raw, float w) {
    __half2* hp = (__half2*)&raw;
    float2 f0 = __half22float2(hp[0]);
    float2 f1 = __half22float2(hp[1]);
    a[0] += w * f0.x; a[1] += w * f0.y; a[2] += w * f1.x; a[3] += w * f1.y;
}

// ---------------- aggregation layer 1 (D=128 fp16 in, fp32 out, +bias, relu) ----
// h rows are UNSCALED; csc weight is w*dinv[src]; self weight dinv[node];
// final scale dinv[node].

__global__ __launch_bounds__(256) void agg1_kernel(const __half* __restrict__ h,
        const float* __restrict__ dinv, const int* __restrict__ offsets,
        const int2* __restrict__ csc, const float* __restrict__ b,
        float* __restrict__ out, int n) {
    int t = threadIdx.x;
    int lane = t & 63;
    int strm = lane >> 4;            // 0..3
    int li = lane & 15;              // half8 index in row (16*8 = 128 dims)
    int node = blockIdx.x * 4 + (t >> 6);
    if (node >= n) return;

    float di = dinv[node];
    float a0[8] = {0,0,0,0,0,0,0,0};
    float a1[8] = {0,0,0,0,0,0,0,0};
    int s = offsets[node], e = offsets[node + 1];

    if (strm == 0) {                 // self-loop: weight dinv[node] * h[node]
        uint4 raw = ((const uint4*)(h + (long)node * HID_DIM))[li];
        acc8(a0, raw, di);
    }

    int p = s + strm;
    for (; p + 4 < e; p += 8) {
        int2 e0 = csc[p], e1 = csc[p + 4];
        uint4 r0 = ((const uint4*)(h + (long)e0.x * HID_DIM))[li];
        uint4 r1 = ((const uint4*)(h + (long)e1.x * HID_DIM))[li];
        acc8(a0, r0, __int_as_float(e0.y));
        acc8(a1, r1, __int_as_float(e1.y));
    }
    if (p < e) {
        int2 e0 = csc[p];
        uint4 r0 = ((const uint4*)(h + (long)e0.x * HID_DIM))[li];
        acc8(a0, r0, __int_as_float(e0.y));
    }
#pragma unroll
    for (int j = 0; j < 8; j++) a0[j] += a1[j];
#pragma unroll
    for (int j = 0; j < 8; j++) a0[j] += __shfl_down(a0[j], 32);
#pragma unroll
    for (int j = 0; j < 8; j++) a0[j] += __shfl_down(a0[j], 16);
    if (strm == 0) {
        float4 bv0 = ((const float4*)b)[li * 2];
        float4 bv1 = ((const float4*)b)[li * 2 + 1];
        float4 o0 = make_float4(fmaxf(di * a0[0] + bv0.x, 0.f), fmaxf(di * a0[1] + bv0.y, 0.f),
                                fmaxf(di * a0[2] + bv0.z, 0.f), fmaxf(di * a0[3] + bv0.w, 0.f));
        float4 o1 = make_float4(fmaxf(di * a0[4] + bv1.x, 0.f), fmaxf(di * a0[5] + bv1.y, 0.f),
                                fmaxf(di * a0[6] + bv1.z, 0.f), fmaxf(di * a0[7] + bv1.w, 0.f));
        float4* dst = (float4*)(out + (long)node * HID_DIM);
        dst[li * 2] = o0;
        dst[li * 2 + 1] = o1;
    }
}

// ---------------- aggregation layer 2 (D=64 fp16 in, fp32 out, +bias) ----------

__global__ __launch_bounds__(256) void agg2_kernel(const __half* __restrict__ h,
        const float* __restrict__ dinv, const int* __restrict__ offsets,
        const int2* __restrict__ csc, const float* __restrict__ b,
        float* __restrict__ out, int n) {
    int t = threadIdx.x;
    int lane = t & 63;
    int strm = lane >> 4;            // 0..3
    int li = lane & 15;              // half4 index in row (16*4 = 64 dims)
    int node = blockIdx.x * 4 + (t >> 6);
    if (node >= n) return;

    float di = dinv[node];
    float a0[4] = {0,0,0,0};
    float a1[4] = {0,0,0,0};
    int s = offsets[node], e = offsets[node + 1];

    if (strm == 0) {
        uint2 raw = ((const uint2*)(h + (long)node * OUT_DIM))[li];
        acc4h(a0, raw, di);
    }

    int p = s + strm;
    for (; p + 4 < e; p += 8) {
        int2 e0 = csc[p], e1 = csc[p + 4];
        uint2 r0 = ((const uint2*)(h + (long)e0.x * OUT_DIM))[li];
        uint2 r1 = ((const uint2*)(h + (long)e1.x * OUT_DIM))[li];
        acc4h(a0, r0, __int_as_float(e0.y));
        acc4h(a1, r1, __int_as_float(e1.y));
    }
    if (p < e) {
        int2 e0 = csc[p];
        uint2 r0 = ((const uint2*)(h + (long)e0.x * OUT_DIM))[li];
        acc4h(a0, r0, __int_as_float(e0.y));
    }
#pragma unroll
    for (int j = 0; j < 4; j++) a0[j] += a1[j];
#pragma unroll
    for (int j = 0; j < 4; j++) a0[j] += __shfl_down(a0[j], 32);
#pragma unroll
    for (int j = 0; j < 4; j++) a0[j] += __shfl_down(a0[j], 16);
    if (strm == 0) {
        float4 bv = ((const float4*)b)[li];
        ((float4*)(out + (long)node * OUT_DIM))[li] =
            make_float4(di * a0[0] + bv.x, di * a0[1] + bv.y,
                        di * a0[2] + bv.z, di * a0[3] + bv.w);
    }
}

// ---------------- launch ----------------

extern "C" void kernel_launch(void* const* d_in, const int* in_sizes, int n_in,
                              void* d_out, int out_size, void* d_ws, size_t ws_size,
                              hipStream_t stream) {
    const float* x  = (const float*)d_in[0];
    const int*   ei = (const int*)d_in[1];
    const float* w  = (const float*)d_in[2];
    const float* W1 = (const float*)d_in[3];
    const float* b1 = (const float*)d_in[4];
    const float* W2 = (const float*)d_in[5];
    const float* b2 = (const float*)d_in[6];
    float* out = (float*)d_out;

    int N = in_sizes[0] / IN_DIM;       // 100000
    int E = in_sizes[2];                // 1600000
    const int* row = ei;
    const int* col = ei + E;

    char* base = (char*)d_ws;
    size_t off = 0;
    auto alloc = [&](size_t bytes) -> void* {
        void* p = base + off;
        off += (bytes + 255) & ~(size_t)255;
        return p;
    };
    unsigned long long* packed = (unsigned long long*)alloc((size_t)N * 8);
    float* dinv     = (float*)alloc((size_t)N * 4);
    int*   cnt      = (int*)  alloc((size_t)N * 4);
    int*   offsets  = (int*)  alloc((size_t)(N + 1) * 4);
    int*   arr      = (int*)  alloc((size_t)E * 4);
    int*   bsum     = (int*)  alloc((size_t)1024 * 4);
    int2*  csc      = (int2*) alloc((size_t)E * 8);
    __half* h       = (__half*)alloc((size_t)N * HID_DIM * 2);  // fp16; reused for h2
    float* hagg     = (float*)alloc((size_t)N * HID_DIM * 4);
    unsigned short* wt1h = (unsigned short*)alloc((size_t)IN_DIM * HID_DIM * 2);
    unsigned short* wt1l = (unsigned short*)alloc((size_t)IN_DIM * HID_DIM * 2);
    unsigned short* wt2h = (unsigned short*)alloc((size_t)HID_DIM * OUT_DIM * 2);
    unsigned short* wt2l = (unsigned short*)alloc((size_t)HID_DIM * OUT_DIM * 2);

    int gN = (N + 255) / 256;
    int gE = (E + 255) / 256;
    int gGemm = (N + 127) / 128;        // 128-row tiles, 128-thread blocks
    int gDeg  = (E + 1023) / 1024;      // 1024 edges per deg-role block
    int gAgg = (N + 3) / 4;
    int nbScan = (N + 1023) / 1024;

    wsplit_kernel<<<(IN_DIM * HID_DIM + 255) / 256, 256, 0, stream>>>(
        W1, wt1h, wt1l, IN_DIM, HID_DIM);
    wsplit_kernel<<<(HID_DIM * OUT_DIM + 255) / 256, 256, 0, stream>>>(
        W2, wt2h, wt2l, HID_DIM, OUT_DIM);
    init_kernel<<<gN, 256, 0, stream>>>(packed, N);
    // fused: GEMM1 (blocks [0,gGemm)) + per-edge deg atomics (blocks [gGemm, gGemm+gDeg))
    gemm_deg_kernel<IN_DIM, HID_DIM, true><<<gGemm + gDeg, 128, 0, stream>>>(
        x, wt1h, wt1l, h, N, gGemm, col, w, packed, arr, E);
    dinv_kernel<<<gN, 256, 0, stream>>>(packed, dinv, cnt, N);
    scan1_kernel<<<nbScan, 256, 0, stream>>>(cnt, bsum, N);
    scan2_kernel<<<1, 1024, 0, stream>>>(bsum, offsets + N, nbScan);
    scan3_kernel<<<nbScan, 256, 0, stream>>>(cnt, bsum, offsets, N);
    fill_csc_kernel<<<gE, 256, 0, stream>>>(row, col, w, dinv, offsets, arr, csc, E);
    agg1_kernel<<<gAgg, 256, 0, stream>>>(h, dinv, offsets, csc, b1, hagg, N);
    gemm_deg_kernel<HID_DIM, OUT_DIM, false><<<gGemm, 128, 0, stream>>>(
        hagg, wt2h, wt2l, h, N, gGemm, col, w, packed, arr, E);
    agg2_kernel<<<gAgg, 256, 0, stream>>>(h, dinv, offsets, csc, b2, out, N);
}